// Round 5
// baseline (175.122 us; speedup 1.0000x reference)
//
#include <hip/hip_runtime.h>
#include <stdint.h>

// ---------------------------------------------------------------------------
// SlidingWindowAttention: B=2, N=2048, C=1024, H=16, Dh=64, window=512 (half=256)
// fp16 MFMA pipeline:
//   prep: x->fp16, W_qkv^T, W_proj^T
//   GEMM1 128x128 BK=64: QKV = Xb @ Wqt^T -> Q(prescaled 0.125*log2e)/K/V planes
//   vtrans: V -> Vt [BH][64][2048]
//   attn: 32x32 MFMA, 256q x 8 waves, 64-key K/V double-buffer (1 barrier/iter),
//         S^T = K.Q^T (col=q -> scalar l), P repacked C-frag -> B-frag IN
//         REGISTERS (shfl_xor 32 + cndmask), O^T = V^T.P, fixed-ref exp2 softmax
//   GEMM2 128x64 BK=64: out = O2 @ Wpt^T + bias (fp32)
// NOTE: dur_us includes ~85us of harness ws-poison fills (2 x 268MB @6.3TB/s);
//       our 5 kernels account for only ~82us of R3's 167.
// ---------------------------------------------------------------------------

typedef _Float16 f16x8 __attribute__((ext_vector_type(8)));
typedef _Float16 f16x4 __attribute__((ext_vector_type(4)));
typedef __fp16   fp16x2n __attribute__((ext_vector_type(2)));  // builtin's native type
typedef float    f32x4 __attribute__((ext_vector_type(4)));
typedef float    f32x16 __attribute__((ext_vector_type(16)));

#define MFMA16(a, b, c) __builtin_amdgcn_mfma_f32_16x16x32_f16((a), (b), (c), 0, 0, 0)
#define MFMA32(a, b, c) __builtin_amdgcn_mfma_f32_32x32x16_f16((a), (b), (c), 0, 0, 0)

__device__ __forceinline__ void gload16(const void* g, void* l) {
  __builtin_amdgcn_global_load_lds(
      (const __attribute__((address_space(1))) void*)g,
      (__attribute__((address_space(3))) void*)l, 16, 0, 0);
}

__device__ __forceinline__ unsigned pk2(float a, float b) {
  fp16x2n t = __builtin_amdgcn_cvt_pkrtz(a, b);
  return __builtin_bit_cast(unsigned, t);
}

// -------------------------- fused prep -------------------------------------
__global__ __launch_bounds__(256) void prep(const float* __restrict__ x,
                                            const float* __restrict__ wqkv,
                                            const float* __restrict__ wproj,
                                            _Float16* __restrict__ Xb,
                                            _Float16* __restrict__ Wqt,
                                            _Float16* __restrict__ Wpt) {
  __shared__ float t[64][65];
  const int id = blockIdx.x, tid = threadIdx.x;
  if (id < 4096) {
    int i = (id * 256 + tid) * 4;
    float4 v = *(const float4*)(x + i);
    f16x4 h;
    h[0] = (_Float16)v.x; h[1] = (_Float16)v.y;
    h[2] = (_Float16)v.z; h[3] = (_Float16)v.w;
    *(f16x4*)(Xb + i) = h;
    return;
  }
  const float* in; _Float16* out; int N, bx, by;
  if (id < 4864) { int tt = id - 4096; in = wqkv; out = Wqt; N = 3072; bx = tt % 48; by = tt / 48; }
  else           { int tt = id - 4864; in = wproj; out = Wpt; N = 1024; bx = tt & 15; by = tt >> 4; }
  const int n0 = bx * 64, k0 = by * 64;
  {
    int j = tid & 63;
#pragma unroll
    for (int p = 0; p < 16; p++) {
      int i = p * 4 + (tid >> 6);
      t[i][j] = in[(size_t)(k0 + i) * N + n0 + j];
    }
  }
  __syncthreads();
  {
    int i = tid & 63;
#pragma unroll
    for (int p = 0; p < 16; p++) {
      int j = p * 4 + (tid >> 6);
      out[(size_t)(n0 + j) * 1024 + k0 + i] = (_Float16)t[i][j];
    }
  }
}

// V [BH][2048][64] -> Vt [BH][64][2048]
__global__ __launch_bounds__(256) void vtrans(const _Float16* __restrict__ V,
                                              _Float16* __restrict__ Vt) {
  __shared__ _Float16 t[64][66];
  const int tid = threadIdx.x;
  const int bh = blockIdx.y, n0 = blockIdx.x * 64;
  const _Float16* Vg = V + (size_t)bh * 131072;
  {
    int dh0 = (tid & 7) * 8;
#pragma unroll
    for (int p = 0; p < 2; p++) {
      int nl = p * 32 + (tid >> 3);
      f16x8 v = *(const f16x8*)(Vg + (size_t)(n0 + nl) * 64 + dh0);
#pragma unroll
      for (int e = 0; e < 8; e++) t[nl][dh0 + e] = v[e];
    }
  }
  __syncthreads();
  {
    int dh = tid >> 2, nb = (tid & 3) * 16;
    f16x8 a, b;
#pragma unroll
    for (int e = 0; e < 8; e++) { a[e] = t[nb + e][dh]; b[e] = t[nb + 8 + e][dh]; }
    _Float16* dst = Vt + (size_t)bh * 131072 + (size_t)dh * 2048 + n0 + nb;
    *(f16x8*)dst = a;
    *(f16x8*)(dst + 8) = b;
  }
}

// -------------------------- GEMM BK=64 -------------------------------------
// C = A[M][K] @ Bt[N][K]^T, BMxBN tiles, 256 thr = 4 waves (2x2).
// LDS rows 128B, 8x16B chunks XOR-swizzled: slot = chunk ^ (row&7).
template <int BM, int BN, int EPI>
__global__ __launch_bounds__(256) void gemm16(const _Float16* __restrict__ A,
                                              const _Float16* __restrict__ Bt,
                                              const int K,
                                              _Float16* __restrict__ oh,
                                              float* __restrict__ of,
                                              const float* __restrict__ bias,
                                              const int Nout) {
  constexpr int RF = BM / 32, CF = BN / 32;
  constexpr int SLABS = (BM + BN) / 8;
  __shared__ __align__(16) char smem[(BM + BN) * 128];
  char* As = smem;
  char* Bs = smem + BM * 128;
  const int tid = threadIdx.x, wave = tid >> 6, lane = tid & 63;
  const int il = lane & 15, ih = lane >> 4;
  const int bm = blockIdx.y * BM, bn = blockIdx.x * BN;
  const int wm = wave >> 1, wn = wave & 1;
  const int rs = lane >> 3, cp = lane & 7;

  f32x4 acc[RF][CF] = {};

  for (int k0 = 0; k0 < K; k0 += 64) {
    __syncthreads();
#pragma unroll
    for (int s0 = 0; s0 < SLABS / 4; s0++) {
      int s = wave + s0 * 4;
      int row = s * 8 + rs;
      int c = cp ^ (row & 7);
      if (row < BM)
        gload16(A + (size_t)(bm + row) * K + k0 + c * 8, As + s * 1024);
      else
        gload16(Bt + (size_t)(bn + row - BM) * K + k0 + c * 8, smem + s * 1024);
    }
    __syncthreads();
#pragma unroll
    for (int ks = 0; ks < 2; ks++) {
      f16x8 af[RF], bf[CF];
#pragma unroll
      for (int rf = 0; rf < RF; rf++) {
        int R = wm * (BM / 2) + rf * 16 + il;
        af[rf] = *(const f16x8*)(As + R * 128 + (((ks * 4 + ih) ^ (R & 7)) * 16));
      }
#pragma unroll
      for (int cf = 0; cf < CF; cf++) {
        int C = wn * (BN / 2) + cf * 16 + il;
        bf[cf] = *(const f16x8*)(Bs + C * 128 + (((ks * 4 + ih) ^ (C & 7)) * 16));
      }
#pragma unroll
      for (int rf = 0; rf < RF; rf++)
#pragma unroll
        for (int cf = 0; cf < CF; cf++)
          acc[rf][cf] = MFMA16(af[rf], bf[cf], acc[rf][cf]);
    }
  }

#pragma unroll
  for (int rf = 0; rf < RF; rf++)
#pragma unroll
    for (int cf = 0; cf < CF; cf++)
#pragma unroll
      for (int r = 0; r < 4; r++) {
        int row = bm + wm * (BM / 2) + rf * 16 + ih * 4 + r;
        int col = bn + wn * (BN / 2) + cf * 16 + il;
        float v = acc[rf][cf][r];
        if (EPI == 0) {
          int sec = col >> 10, cc = col & 1023;
          if (sec == 0) v *= 0.18033688f;  // fold 0.125*log2(e) into Q
          size_t plane = (size_t)(sec * 32 + (row >> 11) * 16 + (cc >> 6));
          oh[plane * 131072 + (size_t)(row & 2047) * 64 + (cc & 63)] = (_Float16)v;
        } else {
          of[(size_t)row * Nout + col] = v + bias[col];
        }
      }
}

// -------------------------- banded flash attention (32x32 MFMA) ------------
// Block: (bh, 256-q tile), 512 thr = 8 waves, wave w owns q rows [32w, 32w+32).
// S^T = K.Q^T: C col=cl=q (scalar l per lane), C row key = 8g+4hl+i2 (reg 4g+i2).
// P C-frag -> PV B-frag (k=8hl+j) entirely in registers:
//   B(ks2) j<4 <- (cl,hl=0) quad[2ks2+recv_hl]; j>=4 <- (cl,hl=1) quad[2ks2+recv_hl]
//   => 4 dword shfl_xor(32) + cndmask per ks2. No P in LDS, no lgkm round-trip.
// O^T = V^T.P (A=Vt rows dh, B=P): C col=q, row=dh -> packed b64 epilogue stores.
// LDS 64KB: Q [0,32K) (prologue only); K/V double buffers at 32K/48K
// (K 8KB + V 8KB each). One barrier per iter; stage(i+1) issued before compute.
// Dead 32-key chunks (|d0|>=288) skipped wave-uniformly; masks only at d0=+-256.
__global__ __launch_bounds__(512) void attn(const _Float16* __restrict__ QKV,
                                            const _Float16* __restrict__ VT,
                                            _Float16* __restrict__ O2) {
  __shared__ __align__(16) char smem[65536];
  char* Qs = smem;
  const int tid = threadIdx.x, wave = tid >> 6, lane = tid & 63;
  const int cl = lane & 31, hl = lane >> 5;
  const int rs = lane >> 3, cp = lane & 7;
  const int q0 = blockIdx.x * 256, bh = blockIdx.y;
  const _Float16* Qg = QKV + (size_t)bh * 131072;
  const _Float16* Kg = QKV + 4194304 + (size_t)bh * 131072;
  const _Float16* Vg = VT + (size_t)bh * 131072;
  const int t0 = (q0 >= 256) ? q0 - 256 : 0;
  const int t1 = (q0 + 512 <= 2048) ? q0 + 512 : 2048;
  const int niter = (t1 - t0) >> 6;

  // stage Q rows [q0,q0+256): 32 slabs, 4 per wave
#pragma unroll
  for (int s0 = 0; s0 < 4; s0++) {
    int s = wave * 4 + s0;
    int row = s * 8 + rs;
    int c = cp ^ (row & 7);
    gload16(Qg + (size_t)(q0 + row) * 64 + c * 8, Qs + s * 1024);
  }
  // stage K/V tile 0 into buf0 (1 K-slab + 1 V-slab per wave)
  {
    char* B0 = smem + 32768;
    int row = wave * 8 + rs;
    int c = cp ^ (row & 7);
    gload16(Kg + (size_t)(t0 + row) * 64 + c * 8, B0 + wave * 1024);
    gload16(Vg + (size_t)row * 2048 + t0 + c * 8, B0 + 8192 + wave * 1024);
  }
  __syncthreads();

  // hoist Q B-frags: B[k=dh][n=q], lane cl = q = 32*wave + cl
  f16x8 bq[4];
  {
    int row = 32 * wave + cl;
#pragma unroll
    for (int ks = 0; ks < 4; ks++)
      bq[ks] = *(const f16x8*)(Qs + row * 128 + (((ks * 2 + hl) ^ (row & 7)) * 16));
  }

  f32x16 oacc[2] = {};
  float l_acc = 0.f;
  const int a0 = q0 + 32 * wave;

  for (int i = 0; i < niter; i++) {
    const int kt = t0 + i * 64;
    char* Bc = smem + 32768 + (i & 1) * 16384;
    if (i + 1 < niter) {  // async prefetch next K/V (lands before next barrier)
      char* Bn = smem + 32768 + ((i + 1) & 1) * 16384;
      int row = wave * 8 + rs;
      int c = cp ^ (row & 7);
      gload16(Kg + (size_t)(kt + 64 + row) * 64 + c * 8, Bn + wave * 1024);
      gload16(Vg + (size_t)row * 2048 + (kt + 64) + c * 8, Bn + 8192 + wave * 1024);
    }
    char* Ksm = Bc;
    char* Vsm = Bc + 8192;
#pragma unroll
    for (int cb = 0; cb < 2; cb++) {
      const int d0 = a0 - (kt + 32 * cb);
      if (d0 >= 288 || d0 <= -288) continue;  // wave-uniform dead chunk
      // S^T for 32 keys x 32 q
      f32x16 st = {};
#pragma unroll
      for (int ks = 0; ks < 4; ks++) {
        int krow = 32 * cb + cl;
        f16x8 ak = *(const f16x8*)(Ksm + krow * 128 + (((ks * 2 + hl) ^ (krow & 7)) * 16));
        st = MFMA32(ak, bq[ks], st);
      }
      // exp2 + band mask + l accumulate + pack quads (key quad g: keys 8g+4hl+..)
      uint32_t q4x[4], q4y[4];
#pragma unroll
      for (int g = 0; g < 4; g++) {
        float v[4];
#pragma unroll
        for (int i2 = 0; i2 < 4; i2++) {
          float e = __builtin_amdgcn_exp2f(st[4 * g + i2]);
          int kl = 8 * g + 4 * hl + i2;
          if (d0 == 256) e = (cl <= kl) ? e : 0.f;
          else if (d0 == -256) e = (cl >= kl) ? e : 0.f;
          l_acc += e;
          v[i2] = e;
        }
        q4x[g] = pk2(v[0], v[1]);
        q4y[g] = pk2(v[2], v[3]);
      }
      // PV: build B-frags in-register (hl-half quad swap), accumulate O^T
#pragma unroll
      for (int ks2 = 0; ks2 < 2; ks2++) {
        uint32_t qax = q4x[2 * ks2], qay = q4y[2 * ks2];
        uint32_t qbx = q4x[2 * ks2 + 1], qby = q4y[2 * ks2 + 1];
        uint32_t rax = __shfl_xor(qax, 32), ray = __shfl_xor(qay, 32);
        uint32_t rbx = __shfl_xor(qbx, 32), rby = __shfl_xor(qby, 32);
        uint32_t lox = hl ? rbx : qax, loy = hl ? rby : qay;
        uint32_t hix = hl ? qbx : rax, hiy = hl ? qby : ray;
        union { uint32_t u[4]; f16x8 h; } bp;
        bp.u[0] = lox; bp.u[1] = loy; bp.u[2] = hix; bp.u[3] = hiy;
#pragma unroll
        for (int db = 0; db < 2; db++) {
          int vrow = 32 * db + cl;
          f16x8 av = *(const f16x8*)(Vsm + vrow * 128 +
                                     (((cb * 4 + ks2 * 2 + hl) ^ (vrow & 7)) * 16));
          oacc[db] = MFMA32(av, bp.h, oacc[db]);
        }
      }
    }
    __syncthreads();  // releases buf(i), guarantees buf(i+1) staged
  }

  // epilogue: merge hl-halves of l, normalize, packed b64 stores
  l_acc += __shfl_xor(l_acc, 32);
  const float inv = 1.0f / l_acc;
  const int b = bh >> 4, h = bh & 15;
  _Float16* dst = O2 + (size_t)(b * 2048 + a0 + cl) * 1024 + h * 64;
#pragma unroll
  for (int db = 0; db < 2; db++)
#pragma unroll
    for (int g = 0; g < 4; g++) {
      uint32_t lo = pk2(oacc[db][4 * g + 0] * inv, oacc[db][4 * g + 1] * inv);
      uint32_t hi = pk2(oacc[db][4 * g + 2] * inv, oacc[db][4 * g + 3] * inv);
      uint2 pkd = {lo, hi};
      *(uint2*)(dst + 32 * db + 8 * g + 4 * hl) = pkd;
    }
}

// -------------------------- host launch ------------------------------------

extern "C" void kernel_launch(void* const* d_in, const int* in_sizes, int n_in,
                              void* d_out, int out_size, void* d_ws, size_t ws_size,
                              hipStream_t stream) {
  const float* x = (const float*)d_in[0];
  const float* wqkv = (const float*)d_in[1];
  const float* wproj = (const float*)d_in[2];
  const float* bproj = (const float*)d_in[3];
  float* out = (float*)d_out;
  char* ws = (char*)d_ws;

  _Float16* Xb  = (_Float16*)(ws);                       // 8 MB [4096][1024]
  _Float16* Wqt = (_Float16*)(ws + (size_t)(8  << 20));  // 6 MB [3072][1024]
  _Float16* Wpt = (_Float16*)(ws + (size_t)(14 << 20));  // 2 MB [1024][1024]
  _Float16* QKV = (_Float16*)(ws + (size_t)(16 << 20));  // 24 MB Q,K,V planes
  _Float16* Vt  = (_Float16*)(ws + (size_t)(40 << 20));  // 8 MB [32][64][2048]
  _Float16* O2  = (_Float16*)(ws);                       // aliases Xb

  prep<<<5120, 256, 0, stream>>>(x, wqkv, wproj, Xb, Wqt, Wpt);
  gemm16<128, 128, 0><<<dim3(24, 32), 256, 0, stream>>>(Xb, Wqt, 1024, QKV, nullptr,
                                                        nullptr, 0);
  vtrans<<<dim3(32, 32), 256, 0, stream>>>(QKV + 8388608, Vt);
  attn<<<dim3(8, 32), 512, 0, stream>>>(QKV, Vt, O2);
  gemm16<128, 64, 1><<<dim3(16, 32), 256, 0, stream>>>(O2, Wpt, 1024, nullptr, out,
                                                       bproj, 1024);
}

// Round 6
// 160.853 us; speedup vs baseline: 1.0887x; 1.0887x over previous
//
#include <hip/hip_runtime.h>
#include <stdint.h>

// ---------------------------------------------------------------------------
// SlidingWindowAttention: B=2, N=2048, C=1024, H=16, Dh=64, window=512 (half=256)
// fp16 MFMA pipeline:
//   prep: x->fp16, W_qkv^T, W_proj^T
//   GEMM1 128x128 BK=64: QKV = Xb @ Wqt^T -> Q(prescaled 0.125*log2e)/K/V planes
//   vtrans: V -> Vt [BH][64][2048]
//   attn v3: 32x32 MFMA, 128q x 8 waves (4 qw x 2 key-half sh), 64-key K/V
//     double-buffer (1 barrier/iter), S^T = K.Q^T (col=q -> scalar l), P via
//     wave-private LDS at 72B pitch (2-way bank alias = free), O^T = V^T.P,
//     fixed-ref exp2 softmax. Grid 512 -> 2+ blocks/CU (50KB LDS).
//   GEMM2 128x64 BK=64: out = O2 @ Wpt^T + bias (fp32)
// Fixed floor: ~46us/iter harness poison fills (256MiB ws + 16MB out).
// ---------------------------------------------------------------------------

typedef _Float16 f16x8 __attribute__((ext_vector_type(8)));
typedef _Float16 f16x4 __attribute__((ext_vector_type(4)));
typedef __fp16   fp16x2n __attribute__((ext_vector_type(2)));
typedef float    f32x2 __attribute__((ext_vector_type(2)));
typedef float    f32x4 __attribute__((ext_vector_type(4)));
typedef float    f32x16 __attribute__((ext_vector_type(16)));

#define MFMA16(a, b, c) __builtin_amdgcn_mfma_f32_16x16x32_f16((a), (b), (c), 0, 0, 0)
#define MFMA32(a, b, c) __builtin_amdgcn_mfma_f32_32x32x16_f16((a), (b), (c), 0, 0, 0)

__device__ __forceinline__ void gload16(const void* g, void* l) {
  __builtin_amdgcn_global_load_lds(
      (const __attribute__((address_space(1))) void*)g,
      (__attribute__((address_space(3))) void*)l, 16, 0, 0);
}

__device__ __forceinline__ unsigned pk2(float a, float b) {
  fp16x2n t = __builtin_amdgcn_cvt_pkrtz(a, b);
  return __builtin_bit_cast(unsigned, t);
}

// -------------------------- fused prep -------------------------------------
__global__ __launch_bounds__(256) void prep(const float* __restrict__ x,
                                            const float* __restrict__ wqkv,
                                            const float* __restrict__ wproj,
                                            _Float16* __restrict__ Xb,
                                            _Float16* __restrict__ Wqt,
                                            _Float16* __restrict__ Wpt) {
  __shared__ float t[64][65];
  const int id = blockIdx.x, tid = threadIdx.x;
  if (id < 4096) {
    int i = (id * 256 + tid) * 4;
    float4 v = *(const float4*)(x + i);
    f16x4 h;
    h[0] = (_Float16)v.x; h[1] = (_Float16)v.y;
    h[2] = (_Float16)v.z; h[3] = (_Float16)v.w;
    *(f16x4*)(Xb + i) = h;
    return;
  }
  const float* in; _Float16* out; int N, bx, by;
  if (id < 4864) { int tt = id - 4096; in = wqkv; out = Wqt; N = 3072; bx = tt % 48; by = tt / 48; }
  else           { int tt = id - 4864; in = wproj; out = Wpt; N = 1024; bx = tt & 15; by = tt >> 4; }
  const int n0 = bx * 64, k0 = by * 64;
  {
    int j = tid & 63;
#pragma unroll
    for (int p = 0; p < 16; p++) {
      int i = p * 4 + (tid >> 6);
      t[i][j] = in[(size_t)(k0 + i) * N + n0 + j];
    }
  }
  __syncthreads();
  {
    int i = tid & 63;
#pragma unroll
    for (int p = 0; p < 16; p++) {
      int j = p * 4 + (tid >> 6);
      out[(size_t)(n0 + j) * 1024 + k0 + i] = (_Float16)t[i][j];
    }
  }
}

// V [BH][2048][64] -> Vt [BH][64][2048]
__global__ __launch_bounds__(256) void vtrans(const _Float16* __restrict__ V,
                                              _Float16* __restrict__ Vt) {
  __shared__ _Float16 t[64][66];
  const int tid = threadIdx.x;
  const int bh = blockIdx.y, n0 = blockIdx.x * 64;
  const _Float16* Vg = V + (size_t)bh * 131072;
  {
    int dh0 = (tid & 7) * 8;
#pragma unroll
    for (int p = 0; p < 2; p++) {
      int nl = p * 32 + (tid >> 3);
      f16x8 v = *(const f16x8*)(Vg + (size_t)(n0 + nl) * 64 + dh0);
#pragma unroll
      for (int e = 0; e < 8; e++) t[nl][dh0 + e] = v[e];
    }
  }
  __syncthreads();
  {
    int dh = tid >> 2, nb = (tid & 3) * 16;
    f16x8 a, b;
#pragma unroll
    for (int e = 0; e < 8; e++) { a[e] = t[nb + e][dh]; b[e] = t[nb + 8 + e][dh]; }
    _Float16* dst = Vt + (size_t)bh * 131072 + (size_t)dh * 2048 + n0 + nb;
    *(f16x8*)dst = a;
    *(f16x8*)(dst + 8) = b;
  }
}

// -------------------------- GEMM BK=64 -------------------------------------
template <int BM, int BN, int EPI>
__global__ __launch_bounds__(256) void gemm16(const _Float16* __restrict__ A,
                                              const _Float16* __restrict__ Bt,
                                              const int K,
                                              _Float16* __restrict__ oh,
                                              float* __restrict__ of,
                                              const float* __restrict__ bias,
                                              const int Nout) {
  constexpr int RF = BM / 32, CF = BN / 32;
  constexpr int SLABS = (BM + BN) / 8;
  __shared__ __align__(16) char smem[(BM + BN) * 128];
  char* As = smem;
  char* Bs = smem + BM * 128;
  const int tid = threadIdx.x, wave = tid >> 6, lane = tid & 63;
  const int il = lane & 15, ih = lane >> 4;
  const int bm = blockIdx.y * BM, bn = blockIdx.x * BN;
  const int wm = wave >> 1, wn = wave & 1;
  const int rs = lane >> 3, cp = lane & 7;

  f32x4 acc[RF][CF] = {};

  for (int k0 = 0; k0 < K; k0 += 64) {
    __syncthreads();
#pragma unroll
    for (int s0 = 0; s0 < SLABS / 4; s0++) {
      int s = wave + s0 * 4;
      int row = s * 8 + rs;
      int c = cp ^ (row & 7);
      if (row < BM)
        gload16(A + (size_t)(bm + row) * K + k0 + c * 8, As + s * 1024);
      else
        gload16(Bt + (size_t)(bn + row - BM) * K + k0 + c * 8, smem + s * 1024);
    }
    __syncthreads();
#pragma unroll
    for (int ks = 0; ks < 2; ks++) {
      f16x8 af[RF], bf[CF];
#pragma unroll
      for (int rf = 0; rf < RF; rf++) {
        int R = wm * (BM / 2) + rf * 16 + il;
        af[rf] = *(const f16x8*)(As + R * 128 + (((ks * 4 + ih) ^ (R & 7)) * 16));
      }
#pragma unroll
      for (int cf = 0; cf < CF; cf++) {
        int C = wn * (BN / 2) + cf * 16 + il;
        bf[cf] = *(const f16x8*)(Bs + C * 128 + (((ks * 4 + ih) ^ (C & 7)) * 16));
      }
#pragma unroll
      for (int rf = 0; rf < RF; rf++)
#pragma unroll
        for (int cf = 0; cf < CF; cf++)
          acc[rf][cf] = MFMA16(af[rf], bf[cf], acc[rf][cf]);
    }
  }

#pragma unroll
  for (int rf = 0; rf < RF; rf++)
#pragma unroll
    for (int cf = 0; cf < CF; cf++)
#pragma unroll
      for (int r = 0; r < 4; r++) {
        int row = bm + wm * (BM / 2) + rf * 16 + ih * 4 + r;
        int col = bn + wn * (BN / 2) + cf * 16 + il;
        float v = acc[rf][cf][r];
        if (EPI == 0) {
          int sec = col >> 10, cc = col & 1023;
          if (sec == 0) v *= 0.18033688f;  // fold 0.125*log2(e) into Q
          size_t plane = (size_t)(sec * 32 + (row >> 11) * 16 + (cc >> 6));
          oh[plane * 131072 + (size_t)(row & 2047) * 64 + (cc & 63)] = (_Float16)v;
        } else {
          of[(size_t)row * Nout + col] = v + bias[col];
        }
      }
}

// -------------------------- banded flash attention v3 ----------------------
// Block: (bh, 128-q tile), 512 thr = 8 waves = 4 qw x 2 sh. Wave: 32 q x its
// 32-key half of each 64-key tile. S^T = K.Q^T (C: col=cl=q, row-key=8g+4hl+i2).
// P wave-private LDS, 32 rows x 72B pitch (bank stride 18 -> 2-way alias, free;
// b64 writes from C-quads, paired b64 reads for PV B-frags). O^T = V^T.P.
// LDS 50KB: P 8x2304=18KB (aliases Q staging, prologue only); K/V dbuf
// 2x(8K+8K) at 18432/34816. One barrier/iter (prefetch -> compute -> barrier).
// d0 = a0-kt-32sh is mult of 32; only d0=+-256 needs lane masks; |d0|>=288 dead.
__global__ __launch_bounds__(512) void attn(const _Float16* __restrict__ QKV,
                                            const _Float16* __restrict__ VT,
                                            _Float16* __restrict__ O2) {
  __shared__ __align__(16) char smem[51200];
  const int tid = threadIdx.x, wave = tid >> 6, lane = tid & 63;
  const int qw = wave >> 1, sh = wave & 1;
  const int cl = lane & 31, hl = lane >> 5;
  const int rs = lane >> 3, cp = lane & 7;
  const int q0 = blockIdx.x * 128, bh = blockIdx.y;
  const _Float16* Qg = QKV + (size_t)bh * 131072;
  const _Float16* Kg = QKV + 4194304 + (size_t)bh * 131072;
  const _Float16* Vg = VT + (size_t)bh * 131072;
  const int t0 = (q0 >= 256) ? q0 - 256 : 0;
  const int t1 = (q0 + 384 <= 2048) ? q0 + 384 : 2048;
  const int niter = (t1 - t0) >> 6;

  // stage Q rows [q0,q0+128) into [0,16K): 16 slabs, 2 per wave
#pragma unroll
  for (int q = 0; q < 2; q++) {
    int s = 2 * wave + q;
    int row = s * 8 + rs;
    int c = cp ^ (row & 7);
    gload16(Qg + (size_t)(q0 + row) * 64 + c * 8, smem + s * 1024);
  }
  // stage K/V tile 0 into buf0 (1 K-slab + 1 V-slab per wave)
  {
    char* B0 = smem + 18432;
    int row = wave * 8 + rs;
    int c = cp ^ (row & 7);
    gload16(Kg + (size_t)(t0 + row) * 64 + c * 8, B0 + wave * 1024);
    gload16(Vg + (size_t)row * 2048 + t0 + c * 8, B0 + 8192 + wave * 1024);
  }
  __syncthreads();

  // hoist Q B-frags: B[k=dh][n=q], q = q0 + 32qw + cl
  f16x8 bq[4];
  {
    int row = 32 * qw + cl;
#pragma unroll
    for (int ks = 0; ks < 4; ks++)
      bq[ks] = *(const f16x8*)(smem + row * 128 + (((ks * 2 + hl) ^ (row & 7)) * 16));
  }
  __syncthreads();  // Q reads done before P overwrites staging region

  char* Pw = smem + wave * 2304;  // 32 rows x 72B
  f32x16 oacc[2] = {};
  float l_acc = 0.f;
  const int a0 = q0 + 32 * qw;

  for (int i = 0; i < niter; i++) {
    const int kt = t0 + i * 64;
    char* Bc = smem + 18432 + (i & 1) * 16384;
    if (i + 1 < niter) {  // async prefetch next K/V into other buffer
      char* Bn = smem + 18432 + ((i + 1) & 1) * 16384;
      int row = wave * 8 + rs;
      int c = cp ^ (row & 7);
      gload16(Kg + (size_t)(kt + 64 + row) * 64 + c * 8, Bn + wave * 1024);
      gload16(Vg + (size_t)row * 2048 + (kt + 64) + c * 8, Bn + 8192 + wave * 1024);
    }
    const int d0 = a0 - (kt + 32 * sh);
    if (d0 < 288 && d0 > -288) {  // wave-uniform live check
      char* Ksm = Bc;
      char* Vsm = Bc + 8192;
      // S^T: 32 keys (this wave's half) x 32 q
      f32x16 st = {};
      {
        const int krow = 32 * sh + cl;
#pragma unroll
        for (int ks = 0; ks < 4; ks++) {
          f16x8 ak = *(const f16x8*)(Ksm + krow * 128 + (((ks * 2 + hl) ^ (krow & 7)) * 16));
          st = MFMA32(ak, bq[ks], st);
        }
      }
      // exp2 + edge masks + l + packed b64 P-writes (quad g: keys 8g+4hl+0..3)
#pragma unroll
      for (int g = 0; g < 4; g++) {
        float v[4];
#pragma unroll
        for (int i2 = 0; i2 < 4; i2++) {
          float e = __builtin_amdgcn_exp2f(st[4 * g + i2]);
          int kl = 8 * g + 4 * hl + i2;
          if (d0 == 256) e = (cl <= kl) ? e : 0.f;
          else if (d0 == -256) e = (cl >= kl) ? e : 0.f;
          l_acc += e;
          v[i2] = e;
        }
        uint2 w2 = {pk2(v[0], v[1]), pk2(v[2], v[3])};
        *(uint2*)(Pw + cl * 72 + 16 * g + 8 * hl) = w2;
      }
      // O^T += V^T . P (wave-private P; same-wave dep, no barrier)
#pragma unroll
      for (int ks2 = 0; ks2 < 2; ks2++) {
        union { uint2 u2[2]; f16x8 h; } bp;
        bp.u2[0] = *(const uint2*)(Pw + cl * 72 + 32 * ks2 + 16 * hl);
        bp.u2[1] = *(const uint2*)(Pw + cl * 72 + 32 * ks2 + 16 * hl + 8);
#pragma unroll
        for (int db = 0; db < 2; db++) {
          int vrow = 32 * db + cl;
          f16x8 av = *(const f16x8*)(Vsm + vrow * 128 +
                                     (((4 * sh + 2 * ks2 + hl) ^ (vrow & 7)) * 16));
          oacc[db] = MFMA32(av, bp.h, oacc[db]);
        }
      }
    }
    __syncthreads();  // releases buf(i), buf(i+1) staged (vmcnt drain at barrier)
  }

  // epilogue: merge hl halves of l per wave, then merge sh waves via LDS.
  // merge buf: per qw, [q=32][dh=64 f32] pitch 264B at smem[0]; l at 34816.
  const float lp = l_acc + __shfl_xor(l_acc, 32);
  char* Mq = smem + qw * 8448;
  if (sh == 1) {
#pragma unroll
    for (int db = 0; db < 2; db++)
#pragma unroll
      for (int g = 0; g < 4; g++) {
        int dh0 = 32 * db + 8 * g + 4 * hl;
        f32x2 a = {oacc[db][4 * g + 0], oacc[db][4 * g + 1]};
        f32x2 b = {oacc[db][4 * g + 2], oacc[db][4 * g + 3]};
        *(f32x2*)(Mq + cl * 264 + dh0 * 4) = a;
        *(f32x2*)(Mq + cl * 264 + dh0 * 4 + 8) = b;
      }
    if (hl == 0) *(float*)(smem + 34816 + (qw * 32 + cl) * 4) = lp;
  }
  __syncthreads();
  if (sh == 0) {
    float lo = *(const float*)(smem + 34816 + (qw * 32 + cl) * 4);
    float inv = 1.0f / (lp + lo);
    const int b = bh >> 4, h = bh & 15;
    _Float16* dst = O2 + (size_t)(b * 2048 + a0 + cl) * 1024 + h * 64;
#pragma unroll
    for (int db = 0; db < 2; db++)
#pragma unroll
      for (int g = 0; g < 4; g++) {
        int dh0 = 32 * db + 8 * g + 4 * hl;
        f32x2 a = *(const f32x2*)(Mq + cl * 264 + dh0 * 4);
        f32x2 b2 = *(const f32x2*)(Mq + cl * 264 + dh0 * 4 + 8);
        uint2 pkd = {pk2((oacc[db][4 * g + 0] + a[0]) * inv,
                         (oacc[db][4 * g + 1] + a[1]) * inv),
                     pk2((oacc[db][4 * g + 2] + b2[0]) * inv,
                         (oacc[db][4 * g + 3] + b2[1]) * inv)};
        *(uint2*)(dst + dh0) = pkd;
      }
  }
}

// -------------------------- host launch ------------------------------------

extern "C" void kernel_launch(void* const* d_in, const int* in_sizes, int n_in,
                              void* d_out, int out_size, void* d_ws, size_t ws_size,
                              hipStream_t stream) {
  const float* x = (const float*)d_in[0];
  const float* wqkv = (const float*)d_in[1];
  const float* wproj = (const float*)d_in[2];
  const float* bproj = (const float*)d_in[3];
  float* out = (float*)d_out;
  char* ws = (char*)d_ws;

  _Float16* Xb  = (_Float16*)(ws);                       // 8 MB [4096][1024]
  _Float16* Wqt = (_Float16*)(ws + (size_t)(8  << 20));  // 6 MB [3072][1024]
  _Float16* Wpt = (_Float16*)(ws + (size_t)(14 << 20));  // 2 MB [1024][1024]
  _Float16* QKV = (_Float16*)(ws + (size_t)(16 << 20));  // 24 MB Q,K,V planes
  _Float16* Vt  = (_Float16*)(ws + (size_t)(40 << 20));  // 8 MB [32][64][2048]
  _Float16* O2  = (_Float16*)(ws);                       // aliases Xb

  prep<<<5120, 256, 0, stream>>>(x, wqkv, wproj, Xb, Wqt, Wpt);
  gemm16<128, 128, 0><<<dim3(24, 32), 256, 0, stream>>>(Xb, Wqt, 1024, QKV, nullptr,
                                                        nullptr, 0);
  vtrans<<<dim3(32, 32), 256, 0, stream>>>(QKV + 8388608, Vt);
  attn<<<dim3(16, 32), 512, 0, stream>>>(QKV, Vt, O2);
  gemm16<128, 64, 1><<<dim3(16, 32), 256, 0, stream>>>(O2, Wpt, 1024, nullptr, out,
                                                       bproj, 1024);
}